// Round 6
// baseline (423.900 us; speedup 1.0000x reference)
//
#include <hip/hip_runtime.h>
#include <hip/hip_bf16.h>

// Problem: B=2, S=2048, D=1024, H=16, hd=64
// ws layout (58 MiB, bf16-element offsets from d_ws):
//   Xb  [0, 4M)        8 MiB  (x in bf16)          -- dead after gemm_qkv
//   AOb [0, 4M)        8 MiB  (attn out bf16)      -- aliases Xb
//   Wt  [4M, 7M)       6 MiB  (Wqkv^T bf16)
//   Qb  [8M, 12M)      8 MiB
//   Kb  [12M, 16M)     8 MiB
//   Vtb [16M, 20M)     8 MiB  (V transposed [B,H,hd,S])
//   MB  [20M, 28M)    16 MiB  (mask+bias fused, blocked 64x64 bf16)
//   Wt2 [28M+..]       2 MiB  (Wout^T bf16)

#define S_LEN 2048
#define DMODEL 1024
#define NH 16
#define HD 64

typedef __bf16 bf16x8 __attribute__((ext_vector_type(8)));
typedef __bf16 bf16x4 __attribute__((ext_vector_type(4)));
typedef __bf16 bf16x2v __attribute__((ext_vector_type(2)));
typedef float f32x4 __attribute__((ext_vector_type(4)));

#define GLD_LDS16(g, l)                                              \
  __builtin_amdgcn_global_load_lds(                                  \
      (const __attribute__((address_space(1))) unsigned int*)(g),    \
      (__attribute__((address_space(3))) unsigned int*)(l), 16, 0, 0)

// ---------------- fp32 -> bf16 convert (x) ----------------
__global__ __launch_bounds__(256) void cvt_x(const float* __restrict__ X,
                                             __bf16* __restrict__ Xb) {
  int i = blockIdx.x * 256 + threadIdx.x;
  float4 v = ((const float4*)X)[i];
  bf16x4 o = {(__bf16)v.x, (__bf16)v.y, (__bf16)v.z, (__bf16)v.w};
  *(bf16x4*)&Xb[(size_t)i * 4] = o;
}

// ------- W[1024,ncols] -> Wt[ncols,1024] bf16 transpose-convert -------
__global__ __launch_bounds__(256) void cvt_wt(const float* __restrict__ W,
                                              __bf16* __restrict__ Wt,
                                              int ncols) {
  __shared__ float tile[64][65];
  const int n0 = blockIdx.x * 64;
  const int k0 = blockIdx.y * 64;
  const int tid = threadIdx.x;
  {
    int c = tid & 63, r4 = tid >> 6;
#pragma unroll
    for (int p = 0; p < 16; ++p) {
      int r = r4 + p * 4;
      tile[r][c] = W[(size_t)(k0 + r) * ncols + n0 + c];
    }
  }
  __syncthreads();
  {
    int cc = (tid & 31) * 2, r8 = tid >> 5;
#pragma unroll
    for (int p = 0; p < 8; ++p) {
      int rr = r8 + p * 8;
      bf16x2v o = {(__bf16)tile[cc][rr], (__bf16)tile[cc + 1][rr]};
      *(bf16x2v*)&Wt[(size_t)(n0 + rr) * 1024 + k0 + cc] = o;
    }
  }
}

// ---------------- fused mask+bias -> blocked bf16 tiles ----------------
__global__ __launch_bounds__(256) void mb_fuse(const float* __restrict__ mask,
                                               const float* __restrict__ bias,
                                               __bf16* __restrict__ MB) {
  const int kt = blockIdx.x, qt = blockIdx.y, b = blockIdx.z;
  const int tid = threadIdx.x;
  const int r = tid >> 2;
  const int c0 = (tid & 3) * 16;
  const size_t qrow = (size_t)(qt * 64 + r);
  const float* mp = mask + qrow * S_LEN + kt * 64 + c0;
  const float* bp =
      bias + (size_t)b * S_LEN * S_LEN + qrow * S_LEN + kt * 64 + c0;
  __bf16* op = MB + (((size_t)(b * 32 + qt) * 32 + kt) * 4096) + r * 64 + c0;
#pragma unroll
  for (int e = 0; e < 4; ++e) {
    float4 m = *(const float4*)(mp + e * 4);
    float4 a = *(const float4*)(bp + e * 4);
    bf16x4 o = {(__bf16)(m.x + a.x), (__bf16)(m.y + a.y), (__bf16)(m.z + a.z),
                (__bf16)(m.w + a.w)};
    *(bf16x4*)(op + e * 4) = o;
  }
}

// ---------------- QKV projection: bf16 MFMA 128x128 tile ----------------
__global__ __launch_bounds__(256) void gemm_qkv_mfma(
    const __bf16* __restrict__ Xb, const __bf16* __restrict__ Wt,
    const float* __restrict__ bqkv, __bf16* __restrict__ Qb,
    __bf16* __restrict__ Kb, __bf16* __restrict__ Vtb) {
  __shared__ __align__(16) __bf16 As[128 * 32];
  __shared__ __align__(16) __bf16 Bs[128 * 32];
  const int tid = threadIdx.x;
  const int w = tid >> 6, lane = tid & 63;
  const int c = lane & 15, quad = lane >> 4;
  const int wm = w >> 1, wn = w & 1;
  const int rowBase = blockIdx.y * 128;
  const int colBase = blockIdx.x * 128;

  f32x4 acc[4][4] = {};

  const __bf16* gA0 =
      Xb + (size_t)(rowBase + w * 32 + (lane >> 2)) * 1024 + (lane & 3) * 8;
  const __bf16* gB0 =
      Wt + (size_t)(colBase + w * 32 + (lane >> 2)) * 1024 + (lane & 3) * 8;
  __bf16* lA0 = &As[(w * 32) * 32];
  __bf16* lB0 = &Bs[(w * 32) * 32];

  for (int k0 = 0; k0 < 1024; k0 += 32) {
    __syncthreads();
#pragma unroll
    for (int p = 0; p < 2; ++p) {
      GLD_LDS16(gA0 + (size_t)p * 16 * 1024 + k0, lA0 + p * 16 * 32);
      GLD_LDS16(gB0 + (size_t)p * 16 * 1024 + k0, lB0 + p * 16 * 32);
    }
    __syncthreads();

    bf16x8 af[4], bfr[4];
#pragma unroll
    for (int mt = 0; mt < 4; ++mt)
      af[mt] = *(const bf16x8*)&As[(wm * 64 + mt * 16 + c) * 32 + quad * 8];
#pragma unroll
    for (int nt = 0; nt < 4; ++nt)
      bfr[nt] = *(const bf16x8*)&Bs[(wn * 64 + nt * 16 + c) * 32 + quad * 8];
#pragma unroll
    for (int mt = 0; mt < 4; ++mt)
#pragma unroll
      for (int nt = 0; nt < 4; ++nt)
        acc[mt][nt] = __builtin_amdgcn_mfma_f32_16x16x32_bf16(
            af[mt], bfr[nt], acc[mt][nt], 0, 0, 0);
  }

#pragma unroll
  for (int mt = 0; mt < 4; ++mt) {
    int row0 = rowBase + wm * 64 + mt * 16 + quad * 4;
#pragma unroll
    for (int nt = 0; nt < 4; ++nt) {
      int col = colBase + wn * 64 + nt * 16 + c;
      float bias = bqkv[col];
      int three = col >> 10;
      int h = (col & 1023) >> 6;
      int d = col & 63;
#pragma unroll
      for (int r = 0; r < 4; ++r) {
        int rr = row0 + r;
        int bb = rr >> 11, s = rr & 2047;
        float val = acc[mt][nt][r] + bias;
        size_t ho = (size_t)(bb * NH + h);
        if (three == 0)
          Qb[(ho * S_LEN + s) * HD + d] = (__bf16)val;
        else if (three == 1)
          Kb[(ho * S_LEN + s) * HD + d] = (__bf16)val;
        else
          Vtb[(ho * HD + d) * S_LEN + s] = (__bf16)val;
      }
    }
  }
}

// ------- MFMA flash attention: fixed-shift softmax + register-prefetch -------
// Pipeline: issue kt+1's K/V/MB global loads into registers BEFORE computing
// kt from LDS; global latency overlaps MFMA+softmax. After compute:
// barrier -> ds_write regs -> barrier. MBs padded to 72 (2-way = free).
__global__ __launch_bounds__(256) void attn_mfma(
    const __bf16* __restrict__ Qb, const __bf16* __restrict__ Kb,
    const __bf16* __restrict__ Vtb, const __bf16* __restrict__ MB,
    __bf16* __restrict__ AOb) {
  const int qt = blockIdx.x, h = blockIdx.y, b = blockIdx.z;
  const int tid = threadIdx.x;
  const int w = tid >> 6;
  const int lane = tid & 63;
  const int c = lane & 15;
  const int quad = lane >> 4;

  __shared__ __align__(16) __bf16 Ks[64 * 72];
  __shared__ __align__(16) __bf16 Vs[64 * 72];   // [feat][key]
  __shared__ __align__(16) __bf16 Ps[64 * 72];   // wave-private strips
  __shared__ __align__(16) __bf16 MBs[64 * 72];  // padded: 2-way only

  const int qbase = qt * 64;
  const size_t headoff = (size_t)(b * NH + h) * S_LEN * HD;
  const __bf16* Qg = Qb + headoff + (size_t)qbase * HD;
  const __bf16* Kg = Kb + headoff;
  const __bf16* Vg = Vtb + headoff;
  const __bf16* MBg = MB + ((size_t)(b * 32 + qt) * 32) * 4096;

  bf16x8 qa0 = *(const bf16x8*)(Qg + (w * 16 + c) * HD + quad * 8);
  bf16x8 qa1 = *(const bf16x8*)(Qg + (w * 16 + c) * HD + quad * 8 + 32);

  // staging geometry: chunk ch = p*256+tid -> row f=ch>>3, col c8=(ch&7)*8
  int f0 = tid >> 3, c80 = (tid & 7) * 8;            // p=0
  int f1 = (256 + tid) >> 3, c81 = c80;              // p=1 (f1 = f0+32)

  f32x4 Oa[4] = {};
  float lsum[4] = {0.f, 0.f, 0.f, 0.f};

  uint4 rK[2], rV[2], rMB[2];
  // preamble: load kt=0, write LDS
  {
    const __bf16* Kt = Kg;
    const __bf16* MBt = MBg;
    rK[0] = *(const uint4*)(Kt + (size_t)f0 * HD + c80);
    rK[1] = *(const uint4*)(Kt + (size_t)f1 * HD + c81);
    rV[0] = *(const uint4*)(Vg + (size_t)f0 * S_LEN + c80);
    rV[1] = *(const uint4*)(Vg + (size_t)f1 * S_LEN + c81);
    rMB[0] = *(const uint4*)(MBt + (size_t)f0 * 64 + c80);
    rMB[1] = *(const uint4*)(MBt + (size_t)f1 * 64 + c81);
    *(uint4*)&Ks[f0 * 72 + c80] = rK[0];
    *(uint4*)&Ks[f1 * 72 + c81] = rK[1];
    *(uint4*)&Vs[f0 * 72 + c80] = rV[0];
    *(uint4*)&Vs[f1 * 72 + c81] = rV[1];
    *(uint4*)&MBs[f0 * 72 + c80] = rMB[0];
    *(uint4*)&MBs[f1 * 72 + c81] = rMB[1];
  }
  __syncthreads();

  for (int kt = 0; kt < 32; ++kt) {
    // issue next tile's loads early (latency hides behind compute below)
    if (kt < 31) {
      const int kb1 = (kt + 1) * 64;
      const __bf16* Kt = Kg + (size_t)kb1 * HD;
      const __bf16* MBt = MBg + (size_t)(kt + 1) * 4096;
      rK[0] = *(const uint4*)(Kt + (size_t)f0 * HD + c80);
      rK[1] = *(const uint4*)(Kt + (size_t)f1 * HD + c81);
      rV[0] = *(const uint4*)(Vg + (size_t)f0 * S_LEN + kb1 + c80);
      rV[1] = *(const uint4*)(Vg + (size_t)f1 * S_LEN + kb1 + c81);
      rMB[0] = *(const uint4*)(MBt + (size_t)f0 * 64 + c80);
      rMB[1] = *(const uint4*)(MBt + (size_t)f1 * 64 + c81);
    }

    // ---- compute kt from LDS ----
    f32x4 sv[4];
#pragma unroll
    for (int ct = 0; ct < 4; ++ct) {
      f32x4 a = {};
      bf16x8 kf0 = *(const bf16x8*)&Ks[(ct * 16 + c) * 72 + quad * 8];
      bf16x8 kf1 = *(const bf16x8*)&Ks[(ct * 16 + c) * 72 + quad * 8 + 32];
      a = __builtin_amdgcn_mfma_f32_16x16x32_bf16(qa0, kf0, a, 0, 0, 0);
      a = __builtin_amdgcn_mfma_f32_16x16x32_bf16(qa1, kf1, a, 0, 0, 0);
      sv[ct] = a;
    }
    // p = exp(s/8 + mb - 8); per-lane row partials of l
#pragma unroll
    for (int ct = 0; ct < 4; ++ct)
#pragma unroll
      for (int r = 0; r < 4; ++r) {
        float mb = (float)MBs[(w * 16 + quad * 4 + r) * 72 + ct * 16 + c];
        float p = __expf(sv[ct][r] * 0.125f + mb - 8.0f);
        lsum[r] += p;
        Ps[(w * 16 + quad * 4 + r) * 72 + ct * 16 + c] = (__bf16)p;
      }
    // PV (Ps wave-private: lgkm wait only, no barrier)
    bf16x8 pf0 = *(const bf16x8*)&Ps[(w * 16 + c) * 72 + quad * 8];
    bf16x8 pf1 = *(const bf16x8*)&Ps[(w * 16 + c) * 72 + quad * 8 + 32];
#pragma unroll
    for (int ft = 0; ft < 4; ++ft) {
      bf16x8 vf0 = *(const bf16x8*)&Vs[(ft * 16 + c) * 72 + quad * 8];
      bf16x8 vf1 = *(const bf16x8*)&Vs[(ft * 16 + c) * 72 + quad * 8 + 32];
      Oa[ft] =
          __builtin_amdgcn_mfma_f32_16x16x32_bf16(pf0, vf0, Oa[ft], 0, 0, 0);
      Oa[ft] =
          __builtin_amdgcn_mfma_f32_16x16x32_bf16(pf1, vf1, Oa[ft], 0, 0, 0);
    }

    // ---- publish kt+1 tile ----
    if (kt < 31) {
      __syncthreads();  // everyone done reading Ks/Vs/MBs for kt
      *(uint4*)&Ks[f0 * 72 + c80] = rK[0];
      *(uint4*)&Ks[f1 * 72 + c81] = rK[1];
      *(uint4*)&Vs[f0 * 72 + c80] = rV[0];
      *(uint4*)&Vs[f1 * 72 + c81] = rV[1];
      *(uint4*)&MBs[f0 * 72 + c80] = rMB[0];
      *(uint4*)&MBs[f1 * 72 + c81] = rMB[1];
      __syncthreads();  // visible to all waves
    }
  }
  // final l reduction across the 16 lanes holding each row
  float invl[4];
#pragma unroll
  for (int r = 0; r < 4; ++r) {
    float t = lsum[r];
    t += __shfl_xor(t, 1);
    t += __shfl_xor(t, 2);
    t += __shfl_xor(t, 4);
    t += __shfl_xor(t, 8);
    invl[r] = 1.0f / t;
  }
#pragma unroll
  for (int ft = 0; ft < 4; ++ft)
#pragma unroll
    for (int r = 0; r < 4; ++r)
      AOb[(size_t)(b * S_LEN + qbase + w * 16 + quad * 4 + r) * DMODEL +
          h * HD + ft * 16 + c] = (__bf16)(Oa[ft][r] * invl[r]);
}

// ---------------- Output projection: bf16 MFMA 128x128 tile ----------------
__global__ __launch_bounds__(256) void gemm_out_mfma(
    const __bf16* __restrict__ AOb, const __bf16* __restrict__ Wt2,
    const float* __restrict__ bout, float* __restrict__ Out) {
  __shared__ __align__(16) __bf16 As[128 * 32];
  __shared__ __align__(16) __bf16 Bs[128 * 32];
  const int tid = threadIdx.x;
  const int w = tid >> 6, lane = tid & 63;
  const int c = lane & 15, quad = lane >> 4;
  const int wm = w >> 1, wn = w & 1;
  const int rowBase = blockIdx.y * 128;
  const int colBase = blockIdx.x * 128;

  f32x4 acc[4][4] = {};

  const __bf16* gA0 =
      AOb + (size_t)(rowBase + w * 32 + (lane >> 2)) * 1024 + (lane & 3) * 8;
  const __bf16* gB0 =
      Wt2 + (size_t)(colBase + w * 32 + (lane >> 2)) * 1024 + (lane & 3) * 8;
  __bf16* lA0 = &As[(w * 32) * 32];
  __bf16* lB0 = &Bs[(w * 32) * 32];

  for (int k0 = 0; k0 < 1024; k0 += 32) {
    __syncthreads();
#pragma unroll
    for (int p = 0; p < 2; ++p) {
      GLD_LDS16(gA0 + (size_t)p * 16 * 1024 + k0, lA0 + p * 16 * 32);
      GLD_LDS16(gB0 + (size_t)p * 16 * 1024 + k0, lB0 + p * 16 * 32);
    }
    __syncthreads();

    bf16x8 af[4], bfr[4];
#pragma unroll
    for (int mt = 0; mt < 4; ++mt)
      af[mt] = *(const bf16x8*)&As[(wm * 64 + mt * 16 + c) * 32 + quad * 8];
#pragma unroll
    for (int nt = 0; nt < 4; ++nt)
      bfr[nt] = *(const bf16x8*)&Bs[(wn * 64 + nt * 16 + c) * 32 + quad * 8];
#pragma unroll
    for (int mt = 0; mt < 4; ++mt)
#pragma unroll
      for (int nt = 0; nt < 4; ++nt)
        acc[mt][nt] = __builtin_amdgcn_mfma_f32_16x16x32_bf16(
            af[mt], bfr[nt], acc[mt][nt], 0, 0, 0);
  }

#pragma unroll
  for (int mt = 0; mt < 4; ++mt) {
    int row0 = rowBase + wm * 64 + mt * 16 + quad * 4;
#pragma unroll
    for (int nt = 0; nt < 4; ++nt) {
      int col = colBase + wn * 64 + nt * 16 + c;
      float bias = bout[col];
#pragma unroll
      for (int r = 0; r < 4; ++r)
        Out[(size_t)(row0 + r) * 1024 + col] = acc[mt][nt][r] + bias;
    }
  }
}

extern "C" void kernel_launch(void* const* d_in, const int* in_sizes, int n_in,
                              void* d_out, int out_size, void* d_ws,
                              size_t ws_size, hipStream_t stream) {
  const float* x = (const float*)d_in[0];
  const float* attn_mask = (const float*)d_in[1];
  const float* attn_bias = (const float*)d_in[2];
  const float* Wqkv = (const float*)d_in[3];
  const float* bqkv = (const float*)d_in[4];
  const float* Wout = (const float*)d_in[5];
  const float* bout = (const float*)d_in[6];
  float* out = (float*)d_out;

  __bf16* base = (__bf16*)d_ws;
  __bf16* Xb = base;                  // [0, 4M)
  __bf16* AOb = base;                 // aliases Xb (disjoint lifetime)
  __bf16* Wt = base + 4194304;        // [4M, 7M)
  __bf16* Qb = base + 8388608;        // [8M, 12M)
  __bf16* Kb = base + 12582912;       // [12M, 16M)
  __bf16* Vtb = base + 16777216;      // [16M, 20M)
  __bf16* MB = base + 20971520;       // [20M, 28M)
  __bf16* Wt2 = base + 29360128;      // [28M, 29M)

  cvt_x<<<4096, 256, 0, stream>>>(x, Xb);
  cvt_wt<<<dim3(48, 16), 256, 0, stream>>>(Wqkv, Wt, 3072);
  cvt_wt<<<dim3(16, 16), 256, 0, stream>>>(Wout, Wt2, 1024);
  mb_fuse<<<dim3(32, 32, 2), 256, 0, stream>>>(attn_mask, attn_bias, MB);
  gemm_qkv_mfma<<<dim3(24, 32), 256, 0, stream>>>(Xb, Wt, bqkv, Qb, Kb, Vtb);
  attn_mfma<<<dim3(32, NH, 2), 256, 0, stream>>>(Qb, Kb, Vtb, MB, AOb);
  gemm_out_mfma<<<dim3(8, 32), 256, 0, stream>>>(AOb, Wt2, bout, out);
}

// Round 7
// 309.946 us; speedup vs baseline: 1.3677x; 1.3677x over previous
//
#include <hip/hip_runtime.h>
#include <hip/hip_bf16.h>

// Problem: B=2, S=2048, D=1024, H=16, hd=64
// ws layout (58 MiB, bf16-element offsets from d_ws):
//   Xb  [0, 4M)        8 MiB  (x in bf16)          -- dead after gemm_qkv
//   AOb [0, 4M)        8 MiB  (attn out bf16)      -- aliases Xb
//   Wt  [4M, 7M)       6 MiB  (Wqkv^T bf16)
//   Qb  [8M, 12M)      8 MiB
//   Kb  [12M, 16M)     8 MiB
//   Vtb [16M, 20M)     8 MiB  (V transposed [B,H,hd,S])
//   MB  [20M, 28M)    16 MiB  (mask+bias fused, per-lane fragment order)
//   Wt2 [28M+..]       2 MiB  (Wout^T bf16)
//
// R6 post-mortem: register-prefetch of K/V/MB across barriers spilled to
// scratch (WRITE_SIZE 8MB -> 787MB). This round: async global_load_lds
// double-buffer (no VGPR hop) + XOR-swizzled LDS (GLD can't pad) + MB in
// per-lane fragment order loaded to short-lived regs.

#define S_LEN 2048
#define DMODEL 1024
#define NH 16
#define HD 64

typedef __bf16 bf16x8 __attribute__((ext_vector_type(8)));
typedef __bf16 bf16x4 __attribute__((ext_vector_type(4)));
typedef __bf16 bf16x2v __attribute__((ext_vector_type(2)));
typedef float f32x4 __attribute__((ext_vector_type(4)));

#define GLD_LDS16(g, l)                                              \
  __builtin_amdgcn_global_load_lds(                                  \
      (const __attribute__((address_space(1))) unsigned int*)(g),    \
      (__attribute__((address_space(3))) unsigned int*)(l), 16, 0, 0)

// ---------------- fp32 -> bf16 convert (x) ----------------
__global__ __launch_bounds__(256) void cvt_x(const float* __restrict__ X,
                                             __bf16* __restrict__ Xb) {
  int i = blockIdx.x * 256 + threadIdx.x;
  float4 v = ((const float4*)X)[i];
  bf16x4 o = {(__bf16)v.x, (__bf16)v.y, (__bf16)v.z, (__bf16)v.w};
  *(bf16x4*)&Xb[(size_t)i * 4] = o;
}

// ------- W[1024,ncols] -> Wt[ncols,1024] bf16 transpose-convert -------
__global__ __launch_bounds__(256) void cvt_wt(const float* __restrict__ W,
                                              __bf16* __restrict__ Wt,
                                              int ncols) {
  __shared__ float tile[64][65];
  const int n0 = blockIdx.x * 64;
  const int k0 = blockIdx.y * 64;
  const int tid = threadIdx.x;
  {
    int c = tid & 63, r4 = tid >> 6;
#pragma unroll
    for (int p = 0; p < 16; ++p) {
      int r = r4 + p * 4;
      tile[r][c] = W[(size_t)(k0 + r) * ncols + n0 + c];
    }
  }
  __syncthreads();
  {
    int cc = (tid & 31) * 2, r8 = tid >> 5;
#pragma unroll
    for (int p = 0; p < 8; ++p) {
      int rr = r8 + p * 8;
      bf16x2v o = {(__bf16)tile[cc][rr], (__bf16)tile[cc + 1][rr]};
      *(bf16x2v*)&Wt[(size_t)(n0 + rr) * 1024 + k0 + cc] = o;
    }
  }
}

// ------- fused mask+bias -> per-lane fragment-order bf16 tiles -------
// For tile (b,qt,kt): thread (w=tid>>6, lane) owns rows w*16+quad*4+r,
// cols ct*16+c (r,ct in 0..3). Stored as 16 contiguous bf16 per lane at
// offset (w*64+lane)*16, element index ct*4+r. attn loads 2 x uint4/lane.
__global__ __launch_bounds__(256) void mb_fuse(const float* __restrict__ mask,
                                               const float* __restrict__ bias,
                                               __bf16* __restrict__ MB) {
  const int kt = blockIdx.x, qt = blockIdx.y, b = blockIdx.z;
  const int tid = threadIdx.x;
  const int w = tid >> 6, lane = tid & 63;
  const int quad = lane >> 4, c = lane & 15;
  const int row0 = qt * 64 + w * 16 + quad * 4;
  const int col0 = kt * 64 + c;
  const float* mp = mask + (size_t)row0 * S_LEN + col0;
  const float* bp =
      bias + (size_t)b * S_LEN * S_LEN + (size_t)row0 * S_LEN + col0;
  __bf16 vals[16];
#pragma unroll
  for (int ct = 0; ct < 4; ++ct)
#pragma unroll
    for (int r = 0; r < 4; ++r)
      vals[ct * 4 + r] = (__bf16)(mp[(size_t)r * S_LEN + ct * 16] +
                                  bp[(size_t)r * S_LEN + ct * 16]);
  __bf16* op =
      MB + (((size_t)(b * 32 + qt) * 32 + kt) * 4096) + (w * 64 + lane) * 16;
  *(bf16x8*)op = *(bf16x8*)&vals[0];
  *(bf16x8*)(op + 8) = *(bf16x8*)&vals[8];
}

// ---------------- QKV projection: bf16 MFMA 128x128 tile ----------------
__global__ __launch_bounds__(256) void gemm_qkv_mfma(
    const __bf16* __restrict__ Xb, const __bf16* __restrict__ Wt,
    const float* __restrict__ bqkv, __bf16* __restrict__ Qb,
    __bf16* __restrict__ Kb, __bf16* __restrict__ Vtb) {
  __shared__ __align__(16) __bf16 As[128 * 32];
  __shared__ __align__(16) __bf16 Bs[128 * 32];
  const int tid = threadIdx.x;
  const int w = tid >> 6, lane = tid & 63;
  const int c = lane & 15, quad = lane >> 4;
  const int wm = w >> 1, wn = w & 1;
  const int rowBase = blockIdx.y * 128;
  const int colBase = blockIdx.x * 128;

  f32x4 acc[4][4] = {};

  const __bf16* gA0 =
      Xb + (size_t)(rowBase + w * 32 + (lane >> 2)) * 1024 + (lane & 3) * 8;
  const __bf16* gB0 =
      Wt + (size_t)(colBase + w * 32 + (lane >> 2)) * 1024 + (lane & 3) * 8;
  __bf16* lA0 = &As[(w * 32) * 32];
  __bf16* lB0 = &Bs[(w * 32) * 32];

  for (int k0 = 0; k0 < 1024; k0 += 32) {
    __syncthreads();
#pragma unroll
    for (int p = 0; p < 2; ++p) {
      GLD_LDS16(gA0 + (size_t)p * 16 * 1024 + k0, lA0 + p * 16 * 32);
      GLD_LDS16(gB0 + (size_t)p * 16 * 1024 + k0, lB0 + p * 16 * 32);
    }
    __syncthreads();

    bf16x8 af[4], bfr[4];
#pragma unroll
    for (int mt = 0; mt < 4; ++mt)
      af[mt] = *(const bf16x8*)&As[(wm * 64 + mt * 16 + c) * 32 + quad * 8];
#pragma unroll
    for (int nt = 0; nt < 4; ++nt)
      bfr[nt] = *(const bf16x8*)&Bs[(wn * 64 + nt * 16 + c) * 32 + quad * 8];
#pragma unroll
    for (int mt = 0; mt < 4; ++mt)
#pragma unroll
      for (int nt = 0; nt < 4; ++nt)
        acc[mt][nt] = __builtin_amdgcn_mfma_f32_16x16x32_bf16(
            af[mt], bfr[nt], acc[mt][nt], 0, 0, 0);
  }

#pragma unroll
  for (int mt = 0; mt < 4; ++mt) {
    int row0 = rowBase + wm * 64 + mt * 16 + quad * 4;
#pragma unroll
    for (int nt = 0; nt < 4; ++nt) {
      int col = colBase + wn * 64 + nt * 16 + c;
      float bias = bqkv[col];
      int three = col >> 10;
      int h = (col & 1023) >> 6;
      int d = col & 63;
#pragma unroll
      for (int r = 0; r < 4; ++r) {
        int rr = row0 + r;
        int bb = rr >> 11, s = rr & 2047;
        float val = acc[mt][nt][r] + bias;
        size_t ho = (size_t)(bb * NH + h);
        if (three == 0)
          Qb[(ho * S_LEN + s) * HD + d] = (__bf16)val;
        else if (three == 1)
          Kb[(ho * S_LEN + s) * HD + d] = (__bf16)val;
        else
          Vtb[(ho * HD + d) * S_LEN + s] = (__bf16)val;
      }
    }
  }
}

// ------- MFMA flash attention: GLD double-buffer + XOR swizzle -------
// K/V tiles DMA'd async into the inactive LDS buffer while computing the
// active one; ONE barrier per iter, after compute, so vmcnt(0) drain finds
// the DMAs landed. LDS chunk (row f, j) holds global chunk (f, j^(f&7))
// -> fragment ds_read_b128 is 2-way (free) without padding.
__global__ __launch_bounds__(256) void attn_mfma(
    const __bf16* __restrict__ Qb, const __bf16* __restrict__ Kb,
    const __bf16* __restrict__ Vtb, const __bf16* __restrict__ MB,
    __bf16* __restrict__ AOb) {
  const int qt = blockIdx.x, h = blockIdx.y, b = blockIdx.z;
  const int tid = threadIdx.x;
  const int w = tid >> 6;
  const int lane = tid & 63;
  const int c = lane & 15;
  const int quad = lane >> 4;

  __shared__ __align__(16) __bf16 Ks[2][64 * 64];
  __shared__ __align__(16) __bf16 Vs[2][64 * 64];  // [feat][key], swizzled
  __shared__ __align__(16) __bf16 Ps[64 * 72];     // wave-private, padded

  const int qbase = qt * 64;
  const size_t headoff = (size_t)(b * NH + h) * S_LEN * HD;
  const __bf16* Qg = Qb + headoff + (size_t)qbase * HD;
  const __bf16* Kg = Kb + headoff;
  const __bf16* Vg = Vtb + headoff;  // [hd][S]
  const __bf16* MBg = MB + ((size_t)(b * 32 + qt) * 32) * 4096;

  // staging geometry: chunk ch = p*256+tid -> row f = ch>>3, col-chunk j =
  // tid&7; global col-chunk is swizzled sj = j ^ (f&7).
  const int f0 = tid >> 3, f1 = f0 + 32;
  const int j = tid & 7;
  const int sj0 = j ^ (f0 & 7);
  const int sj1 = j ^ (f1 & 7);
  const int lds0 = tid * 8;            // element offset of chunk p=0
  const int lds1 = (256 + tid) * 8;    // p=1

  bf16x8 qa0 = *(const bf16x8*)(Qg + (w * 16 + c) * HD + quad * 8);
  bf16x8 qa1 = *(const bf16x8*)(Qg + (w * 16 + c) * HD + quad * 8 + 32);

  // swizzled read offsets for fragments (row&7 == c&7)
  const int rs0 = (quad ^ (c & 7)) * 8;        // k-chunk quad
  const int rs1 = ((quad + 4) ^ (c & 7)) * 8;  // k-chunk quad+4

  f32x4 Oa[4] = {};
  float lsum[4] = {0.f, 0.f, 0.f, 0.f};

  // preamble: DMA kt=0 into buffer 0
  GLD_LDS16(Kg + (size_t)f0 * HD + sj0 * 8, &Ks[0][lds0]);
  GLD_LDS16(Kg + (size_t)f1 * HD + sj1 * 8, &Ks[0][lds1]);
  GLD_LDS16(Vg + (size_t)f0 * S_LEN + sj0 * 8, &Vs[0][lds0]);
  GLD_LDS16(Vg + (size_t)f1 * S_LEN + sj1 * 8, &Vs[0][lds1]);
  __syncthreads();

  for (int kt = 0; kt < 32; ++kt) {
    const int cur = kt & 1, nxt = cur ^ 1;
    // MB fragment prefetch (issued BEFORE the DMAs -> usable at vmcnt(4))
    const __bf16* MBl = MBg + (size_t)kt * 4096 + (w * 64 + lane) * 16;
    bf16x8 rMB0 = *(const bf16x8*)MBl;
    bf16x8 rMB1 = *(const bf16x8*)(MBl + 8);
    // async DMA of kt+1 into the inactive buffer
    if (kt < 31) {
      const int kb1 = (kt + 1) * 64;
      GLD_LDS16(Kg + (size_t)(kb1 + f0) * HD + sj0 * 8, &Ks[nxt][lds0]);
      GLD_LDS16(Kg + (size_t)(kb1 + f1) * HD + sj1 * 8, &Ks[nxt][lds1]);
      GLD_LDS16(Vg + (size_t)f0 * S_LEN + kb1 + sj0 * 8, &Vs[nxt][lds0]);
      GLD_LDS16(Vg + (size_t)f1 * S_LEN + kb1 + sj1 * 8, &Vs[nxt][lds1]);
    }

    // ---- compute kt from LDS[cur] ----
    f32x4 sv[4];
#pragma unroll
    for (int ct = 0; ct < 4; ++ct) {
      f32x4 a = {};
      bf16x8 kf0 = *(const bf16x8*)&Ks[cur][(ct * 16 + c) * 64 + rs0];
      bf16x8 kf1 = *(const bf16x8*)&Ks[cur][(ct * 16 + c) * 64 + rs1];
      a = __builtin_amdgcn_mfma_f32_16x16x32_bf16(qa0, kf0, a, 0, 0, 0);
      a = __builtin_amdgcn_mfma_f32_16x16x32_bf16(qa1, kf1, a, 0, 0, 0);
      sv[ct] = a;
    }
    // p = exp(s/8 + mb - 8); per-lane row partials of l
#pragma unroll
    for (int ct = 0; ct < 4; ++ct)
#pragma unroll
      for (int r = 0; r < 4; ++r) {
        float mb = (ct < 2) ? (float)rMB0[ct * 4 + r]
                            : (float)rMB1[(ct - 2) * 4 + r];
        float p = __expf(sv[ct][r] * 0.125f + mb - 8.0f);
        lsum[r] += p;
        Ps[(w * 16 + quad * 4 + r) * 72 + ct * 16 + c] = (__bf16)p;
      }
    // PV (Ps wave-private: lgkm wait only, no barrier)
    bf16x8 pf0 = *(const bf16x8*)&Ps[(w * 16 + c) * 72 + quad * 8];
    bf16x8 pf1 = *(const bf16x8*)&Ps[(w * 16 + c) * 72 + quad * 8 + 32];
#pragma unroll
    for (int ft = 0; ft < 4; ++ft) {
      bf16x8 vf0 = *(const bf16x8*)&Vs[cur][(ft * 16 + c) * 64 + rs0];
      bf16x8 vf1 = *(const bf16x8*)&Vs[cur][(ft * 16 + c) * 64 + rs1];
      Oa[ft] =
          __builtin_amdgcn_mfma_f32_16x16x32_bf16(pf0, vf0, Oa[ft], 0, 0, 0);
      Oa[ft] =
          __builtin_amdgcn_mfma_f32_16x16x32_bf16(pf1, vf1, Oa[ft], 0, 0, 0);
    }

    // one barrier per iter: all waves done reading LDS[cur]; implicit
    // vmcnt(0) drain completes the kt+1 DMAs (issued ~1800 cy ago).
    __syncthreads();
  }
  // final l reduction across the 16 lanes holding each row
  float invl[4];
#pragma unroll
  for (int r = 0; r < 4; ++r) {
    float t = lsum[r];
    t += __shfl_xor(t, 1);
    t += __shfl_xor(t, 2);
    t += __shfl_xor(t, 4);
    t += __shfl_xor(t, 8);
    invl[r] = 1.0f / t;
  }
#pragma unroll
  for (int ft = 0; ft < 4; ++ft)
#pragma unroll
    for (int r = 0; r < 4; ++r)
      AOb[(size_t)(b * S_LEN + qbase + w * 16 + quad * 4 + r) * DMODEL +
          h * HD + ft * 16 + c] = (__bf16)(Oa[ft][r] * invl[r]);
}

// ---------------- Output projection: bf16 MFMA 128x128 tile ----------------
__global__ __launch_bounds__(256) void gemm_out_mfma(
    const __bf16* __restrict__ AOb, const __bf16* __restrict__ Wt2,
    const float* __restrict__ bout, float* __restrict__ Out) {
  __shared__ __align__(16) __bf16 As[128 * 32];
  __shared__ __align__(16) __bf16 Bs[128 * 32];
  const int tid = threadIdx.x;
  const int w = tid >> 6, lane = tid & 63;
  const int c = lane & 15, quad = lane >> 4;
  const int wm = w >> 1, wn = w & 1;
  const int rowBase = blockIdx.y * 128;
  const int colBase = blockIdx.x * 128;

  f32x4 acc[4][4] = {};

  const __bf16* gA0 =
      AOb + (size_t)(rowBase + w * 32 + (lane >> 2)) * 1024 + (lane & 3) * 8;
  const __bf16* gB0 =
      Wt2 + (size_t)(colBase + w * 32 + (lane >> 2)) * 1024 + (lane & 3) * 8;
  __bf16* lA0 = &As[(w * 32) * 32];
  __bf16* lB0 = &Bs[(w * 32) * 32];

  for (int k0 = 0; k0 < 1024; k0 += 32) {
    __syncthreads();
#pragma unroll
    for (int p = 0; p < 2; ++p) {
      GLD_LDS16(gA0 + (size_t)p * 16 * 1024 + k0, lA0 + p * 16 * 32);
      GLD_LDS16(gB0 + (size_t)p * 16 * 1024 + k0, lB0 + p * 16 * 32);
    }
    __syncthreads();

    bf16x8 af[4], bfr[4];
#pragma unroll
    for (int mt = 0; mt < 4; ++mt)
      af[mt] = *(const bf16x8*)&As[(wm * 64 + mt * 16 + c) * 32 + quad * 8];
#pragma unroll
    for (int nt = 0; nt < 4; ++nt)
      bfr[nt] = *(const bf16x8*)&Bs[(wn * 64 + nt * 16 + c) * 32 + quad * 8];
#pragma unroll
    for (int mt = 0; mt < 4; ++mt)
#pragma unroll
      for (int nt = 0; nt < 4; ++nt)
        acc[mt][nt] = __builtin_amdgcn_mfma_f32_16x16x32_bf16(
            af[mt], bfr[nt], acc[mt][nt], 0, 0, 0);
  }

#pragma unroll
  for (int mt = 0; mt < 4; ++mt) {
    int row0 = rowBase + wm * 64 + mt * 16 + quad * 4;
#pragma unroll
    for (int nt = 0; nt < 4; ++nt) {
      int col = colBase + wn * 64 + nt * 16 + c;
      float bias = bout[col];
#pragma unroll
      for (int r = 0; r < 4; ++r)
        Out[(size_t)(row0 + r) * 1024 + col] = acc[mt][nt][r] + bias;
    }
  }
}

extern "C" void kernel_launch(void* const* d_in, const int* in_sizes, int n_in,
                              void* d_out, int out_size, void* d_ws,
                              size_t ws_size, hipStream_t stream) {
  const float* x = (const float*)d_in[0];
  const float* attn_mask = (const float*)d_in[1];
  const float* attn_bias = (const float*)d_in[2];
  const float* Wqkv = (const float*)d_in[3];
  const float* bqkv = (const float*)d_in[4];
  const float* Wout = (const float*)d_in[5];
  const float* bout = (const float*)d_in[6];
  float* out = (float*)d_out;

  __bf16* base = (__bf16*)d_ws;
  __bf16* Xb = base;                  // [0, 4M)
  __bf16* AOb = base;                 // aliases Xb (disjoint lifetime)
  __bf16* Wt = base + 4194304;        // [4M, 7M)
  __bf16* Qb = base + 8388608;        // [8M, 12M)
  __bf16* Kb = base + 12582912;       // [12M, 16M)
  __bf16* Vtb = base + 16777216;      // [16M, 20M)
  __bf16* MB = base + 20971520;       // [20M, 28M)
  __bf16* Wt2 = base + 29360128;      // [28M, 29M)

  cvt_x<<<4096, 256, 0, stream>>>(x, Xb);
  cvt_wt<<<dim3(48, 16), 256, 0, stream>>>(Wqkv, Wt, 3072);
  cvt_wt<<<dim3(16, 16), 256, 0, stream>>>(Wout, Wt2, 1024);
  mb_fuse<<<dim3(32, 32, 2), 256, 0, stream>>>(attn_mask, attn_bias, MB);
  gemm_qkv_mfma<<<dim3(24, 32), 256, 0, stream>>>(Xb, Wt, bqkv, Qb, Kb, Vtb);
  attn_mfma<<<dim3(32, NH, 2), 256, 0, stream>>>(Qb, Kb, Vtb, MB, AOb);
  gemm_out_mfma<<<dim3(8, 32), 256, 0, stream>>>(AOb, Wt2, bout, out);
}

// Round 8
// 283.201 us; speedup vs baseline: 1.4968x; 1.0944x over previous
//
#include <hip/hip_runtime.h>
#include <hip/hip_bf16.h>

// Problem: B=2, S=2048, D=1024, H=16, hd=64
// ws layout (58 MiB, bf16-element offsets from d_ws):
//   Xb  [0, 4M)        8 MiB  (x in bf16)          -- dead after gemm_qkv
//   AOb [0, 4M)        8 MiB  (attn out bf16)      -- aliases Xb
//   Wt  [4M, 7M)       6 MiB  (Wqkv^T bf16)
//   Qb  [8M, 12M)      8 MiB
//   Kb  [12M, 16M)     8 MiB
//   Vtb [16M, 20M)     8 MiB  (V transposed [B,H,hd,S])
//   MB  [20M, 28M)    16 MiB  (mask+bias, per-lane S^T-fragment order)
//   Wt2 [28M+..]       2 MiB  (Wout^T bf16)
//
// R7 post-mortem: attn is LDS-pipe-bound; the 16 ds_write_b16 P round-trip
// dominates. This round: compute S^T = K*Q^T (operand swap, free), whose
// C-layout IS the B-operand layout of mfma_f32_16x16x16_bf16 (k=quad*4+j),
// so PV = V^T * P^T runs from registers with NO LDS round-trip.

#define S_LEN 2048
#define DMODEL 1024
#define NH 16
#define HD 64

typedef __bf16 bf16x8 __attribute__((ext_vector_type(8)));
typedef __bf16 bf16x4 __attribute__((ext_vector_type(4)));
typedef __bf16 bf16x2v __attribute__((ext_vector_type(2)));
typedef float f32x4 __attribute__((ext_vector_type(4)));
typedef short s16x4 __attribute__((ext_vector_type(4)));

#define GLD_LDS16(g, l)                                              \
  __builtin_amdgcn_global_load_lds(                                  \
      (const __attribute__((address_space(1))) unsigned int*)(g),    \
      (__attribute__((address_space(3))) unsigned int*)(l), 16, 0, 0)

#if __has_builtin(__builtin_amdgcn_mfma_f32_16x16x16bf16_1k)
#define HAVE_MFMA_16x16x16_BF16 1
#else
#define HAVE_MFMA_16x16x16_BF16 0
#endif

// ---------------- fp32 -> bf16 convert (x) ----------------
__global__ __launch_bounds__(256) void cvt_x(const float* __restrict__ X,
                                             __bf16* __restrict__ Xb) {
  int i = blockIdx.x * 256 + threadIdx.x;
  float4 v = ((const float4*)X)[i];
  bf16x4 o = {(__bf16)v.x, (__bf16)v.y, (__bf16)v.z, (__bf16)v.w};
  *(bf16x4*)&Xb[(size_t)i * 4] = o;
}

// ------- W[1024,ncols] -> Wt[ncols,1024] bf16 transpose-convert -------
__global__ __launch_bounds__(256) void cvt_wt(const float* __restrict__ W,
                                              __bf16* __restrict__ Wt,
                                              int ncols) {
  __shared__ float tile[64][65];
  const int n0 = blockIdx.x * 64;
  const int k0 = blockIdx.y * 64;
  const int tid = threadIdx.x;
  {
    int c = tid & 63, r4 = tid >> 6;
#pragma unroll
    for (int p = 0; p < 16; ++p) {
      int r = r4 + p * 4;
      tile[r][c] = W[(size_t)(k0 + r) * ncols + n0 + c];
    }
  }
  __syncthreads();
  {
    int cc = (tid & 31) * 2, r8 = tid >> 5;
#pragma unroll
    for (int p = 0; p < 8; ++p) {
      int rr = r8 + p * 8;
      bf16x2v o = {(__bf16)tile[cc][rr], (__bf16)tile[cc + 1][rr]};
      *(bf16x2v*)&Wt[(size_t)(n0 + rr) * 1024 + k0 + cc] = o;
    }
  }
}

// ------- fused mask+bias -> per-lane S^T-fragment-order bf16 tiles -------
// attn thread (w, lane=quad*16+c) owns qrow = qt*64+w*16+c and kcols
// kt*64 + ct*16 + quad*4 + r. Element [ct*4+r] of its 16-value fragment.
__global__ __launch_bounds__(256) void mb_fuse(const float* __restrict__ mask,
                                               const float* __restrict__ bias,
                                               __bf16* __restrict__ MB) {
  const int kt = blockIdx.x, qt = blockIdx.y, b = blockIdx.z;
  const int tid = threadIdx.x;
  const int w = tid >> 6, lane = tid & 63;
  const int quad = lane >> 4, c = lane & 15;
  const size_t qrow = (size_t)(qt * 64 + w * 16 + c);
  const int col0 = kt * 64 + quad * 4;
  const float* mp = mask + qrow * S_LEN + col0;
  const float* bp = bias + (size_t)b * S_LEN * S_LEN + qrow * S_LEN + col0;
  __bf16 vals[16];
#pragma unroll
  for (int ct = 0; ct < 4; ++ct) {
    float4 m = *(const float4*)(mp + ct * 16);
    float4 a = *(const float4*)(bp + ct * 16);
    vals[ct * 4 + 0] = (__bf16)(m.x + a.x);
    vals[ct * 4 + 1] = (__bf16)(m.y + a.y);
    vals[ct * 4 + 2] = (__bf16)(m.z + a.z);
    vals[ct * 4 + 3] = (__bf16)(m.w + a.w);
  }
  __bf16* op =
      MB + (((size_t)(b * 32 + qt) * 32 + kt) * 4096) + (w * 64 + lane) * 16;
  *(bf16x8*)op = *(bf16x8*)&vals[0];
  *(bf16x8*)(op + 8) = *(bf16x8*)&vals[8];
}

// ---------------- QKV projection: bf16 MFMA 128x128 tile ----------------
__global__ __launch_bounds__(256) void gemm_qkv_mfma(
    const __bf16* __restrict__ Xb, const __bf16* __restrict__ Wt,
    const float* __restrict__ bqkv, __bf16* __restrict__ Qb,
    __bf16* __restrict__ Kb, __bf16* __restrict__ Vtb) {
  __shared__ __align__(16) __bf16 As[128 * 32];
  __shared__ __align__(16) __bf16 Bs[128 * 32];
  const int tid = threadIdx.x;
  const int w = tid >> 6, lane = tid & 63;
  const int c = lane & 15, quad = lane >> 4;
  const int wm = w >> 1, wn = w & 1;
  const int rowBase = blockIdx.y * 128;
  const int colBase = blockIdx.x * 128;

  f32x4 acc[4][4] = {};

  const __bf16* gA0 =
      Xb + (size_t)(rowBase + w * 32 + (lane >> 2)) * 1024 + (lane & 3) * 8;
  const __bf16* gB0 =
      Wt + (size_t)(colBase + w * 32 + (lane >> 2)) * 1024 + (lane & 3) * 8;
  __bf16* lA0 = &As[(w * 32) * 32];
  __bf16* lB0 = &Bs[(w * 32) * 32];

  for (int k0 = 0; k0 < 1024; k0 += 32) {
    __syncthreads();
#pragma unroll
    for (int p = 0; p < 2; ++p) {
      GLD_LDS16(gA0 + (size_t)p * 16 * 1024 + k0, lA0 + p * 16 * 32);
      GLD_LDS16(gB0 + (size_t)p * 16 * 1024 + k0, lB0 + p * 16 * 32);
    }
    __syncthreads();

    bf16x8 af[4], bfr[4];
#pragma unroll
    for (int mt = 0; mt < 4; ++mt)
      af[mt] = *(const bf16x8*)&As[(wm * 64 + mt * 16 + c) * 32 + quad * 8];
#pragma unroll
    for (int nt = 0; nt < 4; ++nt)
      bfr[nt] = *(const bf16x8*)&Bs[(wn * 64 + nt * 16 + c) * 32 + quad * 8];
#pragma unroll
    for (int mt = 0; mt < 4; ++mt)
#pragma unroll
      for (int nt = 0; nt < 4; ++nt)
        acc[mt][nt] = __builtin_amdgcn_mfma_f32_16x16x32_bf16(
            af[mt], bfr[nt], acc[mt][nt], 0, 0, 0);
  }

#pragma unroll
  for (int mt = 0; mt < 4; ++mt) {
    int row0 = rowBase + wm * 64 + mt * 16 + quad * 4;
#pragma unroll
    for (int nt = 0; nt < 4; ++nt) {
      int col = colBase + wn * 64 + nt * 16 + c;
      float bias = bqkv[col];
      int three = col >> 10;
      int h = (col & 1023) >> 6;
      int d = col & 63;
#pragma unroll
      for (int r = 0; r < 4; ++r) {
        int rr = row0 + r;
        int bb = rr >> 11, s = rr & 2047;
        float val = acc[mt][nt][r] + bias;
        size_t ho = (size_t)(bb * NH + h);
        if (three == 0)
          Qb[(ho * S_LEN + s) * HD + d] = (__bf16)val;
        else if (three == 1)
          Kb[(ho * S_LEN + s) * HD + d] = (__bf16)val;
        else
          Vtb[(ho * HD + d) * S_LEN + s] = (__bf16)val;
      }
    }
  }
}

// ------- MFMA flash attention: S^T dataflow, no P LDS round-trip -------
// S^T = K*Q^T via mfma(A=kf, B=qa): lane holds S^T[kcol=ct*16+quad*4+r][qrow=c].
// That IS the B-operand layout of mfma_f32_16x16x16_bf16 (k=quad*4+j), so
// PV: O^T = V^T * P^T accumulates straight from registers.
// K/V double-buffered via async global_load_lds with XOR chunk swizzle.
__global__ __launch_bounds__(256) void attn_mfma(
    const __bf16* __restrict__ Qb, const __bf16* __restrict__ Kb,
    const __bf16* __restrict__ Vtb, const __bf16* __restrict__ MB,
    __bf16* __restrict__ AOb) {
  const int qt = blockIdx.x, h = blockIdx.y, b = blockIdx.z;
  const int tid = threadIdx.x;
  const int w = tid >> 6;
  const int lane = tid & 63;
  const int c = lane & 15;
  const int quad = lane >> 4;

  __shared__ __align__(16) __bf16 Ks[2][64 * 64];
  __shared__ __align__(16) __bf16 Vs[2][64 * 64];  // [feat][key], swizzled
#if !HAVE_MFMA_16x16x16_BF16
  __shared__ __align__(16) __bf16 P2[4][16 * 72];  // fallback: P^T per wave
#endif

  const int qbase = qt * 64;
  const size_t headoff = (size_t)(b * NH + h) * S_LEN * HD;
  const __bf16* Qg = Qb + headoff + (size_t)qbase * HD;
  const __bf16* Kg = Kb + headoff;
  const __bf16* Vg = Vtb + headoff;  // [hd][S]
  const __bf16* MBg = MB + ((size_t)(b * 32 + qt) * 32) * 4096;

  // staging geometry (chunk ch = p*256+tid -> row f, col-chunk j, swizzled)
  const int f0 = tid >> 3, f1 = f0 + 32;
  const int j = tid & 7;
  const int sj0 = j ^ (f0 & 7);
  const int sj1 = j ^ (f1 & 7);
  const int lds0 = tid * 8;
  const int lds1 = (256 + tid) * 8;

  // Q fragment: lane holds Q[qrow=w*16+c][d=quad*8+j] (loop-invariant)
  bf16x8 qa0 = *(const bf16x8*)(Qg + (w * 16 + c) * HD + quad * 8);
  bf16x8 qa1 = *(const bf16x8*)(Qg + (w * 16 + c) * HD + quad * 8 + 32);

  // swizzled b128 read offsets (row&7 == c&7)
  const int rs0 = (quad ^ (c & 7)) * 8;
  const int rs1 = ((quad + 4) ^ (c & 7)) * 8;

  f32x4 Oa[4] = {};  // O^T[d=ft*16+quad*4+r][qrow=c]
  float lsum = 0.f;

  // preamble: DMA kt=0 into buffer 0
  GLD_LDS16(Kg + (size_t)f0 * HD + sj0 * 8, &Ks[0][lds0]);
  GLD_LDS16(Kg + (size_t)f1 * HD + sj1 * 8, &Ks[0][lds1]);
  GLD_LDS16(Vg + (size_t)f0 * S_LEN + sj0 * 8, &Vs[0][lds0]);
  GLD_LDS16(Vg + (size_t)f1 * S_LEN + sj1 * 8, &Vs[0][lds1]);
  __syncthreads();

  for (int kt = 0; kt < 32; ++kt) {
    const int cur = kt & 1, nxt = cur ^ 1;
    // MB fragment prefetch (short liveness; issued before the DMAs)
    const __bf16* MBl = MBg + (size_t)kt * 4096 + (w * 64 + lane) * 16;
    bf16x8 rMB0 = *(const bf16x8*)MBl;
    bf16x8 rMB1 = *(const bf16x8*)(MBl + 8);
    // async DMA of kt+1 into the inactive buffer
    if (kt < 31) {
      const int kb1 = (kt + 1) * 64;
      GLD_LDS16(Kg + (size_t)(kb1 + f0) * HD + sj0 * 8, &Ks[nxt][lds0]);
      GLD_LDS16(Kg + (size_t)(kb1 + f1) * HD + sj1 * 8, &Ks[nxt][lds1]);
      GLD_LDS16(Vg + (size_t)f0 * S_LEN + kb1 + sj0 * 8, &Vs[nxt][lds0]);
      GLD_LDS16(Vg + (size_t)f1 * S_LEN + kb1 + sj1 * 8, &Vs[nxt][lds1]);
    }

    // ---- S^T = K * Q^T ----
    f32x4 sv[4];
#pragma unroll
    for (int ct = 0; ct < 4; ++ct) {
      f32x4 a = {};
      bf16x8 kf0 = *(const bf16x8*)&Ks[cur][(ct * 16 + c) * 64 + rs0];
      bf16x8 kf1 = *(const bf16x8*)&Ks[cur][(ct * 16 + c) * 64 + rs1];
      a = __builtin_amdgcn_mfma_f32_16x16x32_bf16(kf0, qa0, a, 0, 0, 0);
      a = __builtin_amdgcn_mfma_f32_16x16x32_bf16(kf1, qa1, a, 0, 0, 0);
      sv[ct] = a;
    }
    // p = exp(s/8 + mb - 8), scalar row-partial lsum, pack P^T fragments
    s16x4 pb[4];
#pragma unroll
    for (int ct = 0; ct < 4; ++ct) {
      __bf16 t4[4];
#pragma unroll
      for (int r = 0; r < 4; ++r) {
        float mb = (ct < 2) ? (float)rMB0[ct * 4 + r]
                            : (float)rMB1[(ct - 2) * 4 + r];
        float p = __expf(sv[ct][r] * 0.125f + mb - 8.0f);
        lsum += p;
        t4[r] = (__bf16)p;
      }
      pb[ct] = *(s16x4*)t4;
    }

#if HAVE_MFMA_16x16x16_BF16
    // ---- O^T += V^T * P^T, K=16 chunks, straight from registers ----
#pragma unroll
    for (int ft = 0; ft < 4; ++ft) {
      const int fr = ft * 16 + c;
#pragma unroll
      for (int ct = 0; ct < 4; ++ct) {
        const int chunk = ((ct * 2 + (quad >> 1)) ^ (fr & 7)) * 8 +
                          (quad & 1) * 4;
        s16x4 vf = *(const s16x4*)&Vs[cur][fr * 64 + chunk];
        Oa[ft] = __builtin_amdgcn_mfma_f32_16x16x16bf16_1k(vf, pb[ct],
                                                           Oa[ft], 0, 0, 0);
      }
    }
#else
    // ---- fallback: P^T via wave-private LDS (b64 writes, b128 reads) ----
#pragma unroll
    for (int ct = 0; ct < 4; ++ct)
      *(bf16x4*)&P2[w][c * 72 + ct * 16 + quad * 4] = *(bf16x4*)&pb[ct];
    bf16x8 pf0 = *(const bf16x8*)&P2[w][c * 72 + quad * 8];
    bf16x8 pf1 = *(const bf16x8*)&P2[w][c * 72 + 32 + quad * 8];
#pragma unroll
    for (int ft = 0; ft < 4; ++ft) {
      const int fr = ft * 16 + c;
      bf16x8 vf0 = *(const bf16x8*)&Vs[cur][fr * 64 + rs0];
      bf16x8 vf1 = *(const bf16x8*)&Vs[cur][fr * 64 + rs1];
      Oa[ft] =
          __builtin_amdgcn_mfma_f32_16x16x32_bf16(vf0, pf0, Oa[ft], 0, 0, 0);
      Oa[ft] =
          __builtin_amdgcn_mfma_f32_16x16x32_bf16(vf1, pf1, Oa[ft], 0, 0, 0);
    }
#endif

    // one barrier per iter: LDS[cur] reads done; implicit vmcnt(0) completes
    // the kt+1 DMAs (issued before ~1800 cy of compute).
    __syncthreads();
  }
  // full row sum: partials live in the 4 quads of each column c
  lsum += __shfl_xor(lsum, 16);
  lsum += __shfl_xor(lsum, 32);
  const float invl = 1.0f / lsum;
  // O^T store: lane c owns qrow w*16+c, d = ft*16+quad*4+r (b64 stores)
  __bf16* orow =
      AOb + (size_t)(b * S_LEN + qbase + w * 16 + c) * DMODEL + h * HD;
#pragma unroll
  for (int ft = 0; ft < 4; ++ft) {
    __bf16 t4[4];
#pragma unroll
    for (int r = 0; r < 4; ++r) t4[r] = (__bf16)(Oa[ft][r] * invl);
    *(bf16x4*)(orow + ft * 16 + quad * 4) = *(bf16x4*)t4;
  }
}

// ---------------- Output projection: bf16 MFMA 128x128 tile ----------------
__global__ __launch_bounds__(256) void gemm_out_mfma(
    const __bf16* __restrict__ AOb, const __bf16* __restrict__ Wt2,
    const float* __restrict__ bout, float* __restrict__ Out) {
  __shared__ __align__(16) __bf16 As[128 * 32];
  __shared__ __align__(16) __bf16 Bs[128 * 32];
  const int tid = threadIdx.x;
  const int w = tid >> 6, lane = tid & 63;
  const int c = lane & 15, quad = lane >> 4;
  const int wm = w >> 1, wn = w & 1;
  const int rowBase = blockIdx.y * 128;
  const int colBase = blockIdx.x * 128;

  f32x4 acc[4][4] = {};

  const __bf16* gA0 =
      AOb + (size_t)(rowBase + w * 32 + (lane >> 2)) * 1024 + (lane & 3) * 8;
  const __bf16* gB0 =
      Wt2 + (size_t)(colBase + w * 32 + (lane >> 2)) * 1024 + (lane & 3) * 8;
  __bf16* lA0 = &As[(w * 32) * 32];
  __bf16* lB0 = &Bs[(w * 32) * 32];

  for (int k0 = 0; k0 < 1024; k0 += 32) {
    __syncthreads();
#pragma unroll
    for (int p = 0; p < 2; ++p) {
      GLD_LDS16(gA0 + (size_t)p * 16 * 1024 + k0, lA0 + p * 16 * 32);
      GLD_LDS16(gB0 + (size_t)p * 16 * 1024 + k0, lB0 + p * 16 * 32);
    }
    __syncthreads();

    bf16x8 af[4], bfr[4];
#pragma unroll
    for (int mt = 0; mt < 4; ++mt)
      af[mt] = *(const bf16x8*)&As[(wm * 64 + mt * 16 + c) * 32 + quad * 8];
#pragma unroll
    for (int nt = 0; nt < 4; ++nt)
      bfr[nt] = *(const bf16x8*)&Bs[(wn * 64 + nt * 16 + c) * 32 + quad * 8];
#pragma unroll
    for (int mt = 0; mt < 4; ++mt)
#pragma unroll
      for (int nt = 0; nt < 4; ++nt)
        acc[mt][nt] = __builtin_amdgcn_mfma_f32_16x16x32_bf16(
            af[mt], bfr[nt], acc[mt][nt], 0, 0, 0);
  }

#pragma unroll
  for (int mt = 0; mt < 4; ++mt) {
    int row0 = rowBase + wm * 64 + mt * 16 + quad * 4;
#pragma unroll
    for (int nt = 0; nt < 4; ++nt) {
      int col = colBase + wn * 64 + nt * 16 + c;
      float bias = bout[col];
#pragma unroll
      for (int r = 0; r < 4; ++r)
        Out[(size_t)(row0 + r) * 1024 + col] = acc[mt][nt][r] + bias;
    }
  }
}

extern "C" void kernel_launch(void* const* d_in, const int* in_sizes, int n_in,
                              void* d_out, int out_size, void* d_ws,
                              size_t ws_size, hipStream_t stream) {
  const float* x = (const float*)d_in[0];
  const float* attn_mask = (const float*)d_in[1];
  const float* attn_bias = (const float*)d_in[2];
  const float* Wqkv = (const float*)d_in[3];
  const float* bqkv = (const float*)d_in[4];
  const float* Wout = (const float*)d_in[5];
  const float* bout = (const float*)d_in[6];
  float* out = (float*)d_out;

  __bf16* base = (__bf16*)d_ws;
  __bf16* Xb = base;                  // [0, 4M)
  __bf16* AOb = base;                 // aliases Xb (disjoint lifetime)
  __bf16* Wt = base + 4194304;        // [4M, 7M)
  __bf16* Qb = base + 8388608;        // [8M, 12M)
  __bf16* Kb = base + 12582912;       // [12M, 16M)
  __bf16* Vtb = base + 16777216;      // [16M, 20M)
  __bf16* MB = base + 20971520;       // [20M, 28M)
  __bf16* Wt2 = base + 29360128;      // [28M, 29M)

  cvt_x<<<4096, 256, 0, stream>>>(x, Xb);
  cvt_wt<<<dim3(48, 16), 256, 0, stream>>>(Wqkv, Wt, 3072);
  cvt_wt<<<dim3(16, 16), 256, 0, stream>>>(Wout, Wt2, 1024);
  mb_fuse<<<dim3(32, 32, 2), 256, 0, stream>>>(attn_mask, attn_bias, MB);
  gemm_qkv_mfma<<<dim3(24, 32), 256, 0, stream>>>(Xb, Wt, bqkv, Qb, Kb, Vtb);
  attn_mfma<<<dim3(32, NH, 2), 256, 0, stream>>>(Qb, Kb, Vtb, MB, AOb);
  gemm_out_mfma<<<dim3(8, 32), 256, 0, stream>>>(AOb, Wt2, bout, out);
}